// Round 1
// baseline (1053.546 us; speedup 1.0000x reference)
//
#include <hip/hip_runtime.h>
#include <hip/hip_bf16.h>

// BitNet 4-layer MLP forward, MI355X.
// Strategy: quantized matmuls are integer-exact -> do them as bf16 MFMA with
// integer-valued operands (q_x in [-128,127], q_w in {-1,0,1}); fp32 accum is
// exact (sums < 2^24). Epilogue applies (1/s_x[row])*(1/s_w) + bias (+tanh).

typedef __attribute__((ext_vector_type(8))) short bf16x8_t;
typedef __attribute__((ext_vector_type(4))) float f32x4_t;

#define GLDS16(g, l) __builtin_amdgcn_global_load_lds( \
    (const __attribute__((address_space(1))) unsigned int*)(g), \
    (__attribute__((address_space(3))) unsigned int*)(l), 16, 0, 0)

static __device__ __forceinline__ unsigned short f2bf_exact(float f) {
  // exact for integer-valued floats |f| <= 256 and +-1/0 — plain truncation
  return (unsigned short)(__builtin_bit_cast(unsigned int, f) >> 16);
}

// ---------------- weight abs-mean (deterministic two-stage fp64) ------------
__global__ __launch_bounds__(256) void absmean_part_k(
    const float* __restrict__ W, int n4, double* __restrict__ part)
{
  double s = 0.0;
  const int stride = gridDim.x * 256;
  for (int i = blockIdx.x * 256 + threadIdx.x; i < n4; i += stride) {
    float4 v = ((const float4*)W)[i];
    s += (double)fabsf(v.x); s += (double)fabsf(v.y);
    s += (double)fabsf(v.z); s += (double)fabsf(v.w);
  }
  __shared__ double sd[256];
  sd[threadIdx.x] = s;
  __syncthreads();
  for (int st = 128; st > 0; st >>= 1) {
    if (threadIdx.x < st) sd[threadIdx.x] += sd[threadIdx.x + st];
    __syncthreads();
  }
  if (threadIdx.x == 0) part[blockIdx.x] = sd[0];
}

__global__ __launch_bounds__(256) void absmean_fin_k(
    const double* __restrict__ part, int nPart, double n,
    float* __restrict__ wsc, int widx)
{
  __shared__ double sd[256];
  double s = 0.0;
  for (int i = threadIdx.x; i < nPart; i += 256) s += part[i];
  sd[threadIdx.x] = s;
  __syncthreads();
  for (int st = 128; st > 0; st >>= 1) {
    if (threadIdx.x < st) sd[threadIdx.x] += sd[threadIdx.x + st];
    __syncthreads();
  }
  if (threadIdx.x == 0) {
    float mean = (float)(sd[0] / n);
    float scale = 1.f / fmaxf(mean, 1e-5f);   // matches reference fp32 math
    wsc[widx * 2]     = scale;                // used for quantization
    wsc[widx * 2 + 1] = 1.f / scale;          // used in epilogue (== wq magnitude)
  }
}

// ---------------- weight ternary quantization to bf16 {-1,0,1} --------------
__global__ __launch_bounds__(256) void quant_w_k(
    const float* __restrict__ W, unsigned short* __restrict__ Wq,
    const float* __restrict__ wsc, int widx, int n4)
{
  const float s = wsc[widx * 2];
  const int stride = gridDim.x * 256;
  for (int i = blockIdx.x * 256 + threadIdx.x; i < n4; i += stride) {
    float4 v = ((const float4*)W)[i];
    ushort4 u;
    u.x = f2bf_exact(fminf(fmaxf(rintf(v.x * s), -1.f), 1.f));
    u.y = f2bf_exact(fminf(fmaxf(rintf(v.y * s), -1.f), 1.f));
    u.z = f2bf_exact(fminf(fmaxf(rintf(v.z * s), -1.f), 1.f));
    u.w = f2bf_exact(fminf(fmaxf(rintf(v.w * s), -1.f), 1.f));
    ((ushort4*)Wq)[i] = u;
  }
}

// ---------------- per-row activation quantization to bf16 integers ----------
template<int D>
__global__ __launch_bounds__(256) void act_quant_k(
    const float* __restrict__ X, unsigned short* __restrict__ Xq,
    float* __restrict__ inv_sa)
{
  constexpr int PER = D / 1024;     // float4 chunks per thread (256 threads)
  const int row = blockIdx.x, tid = threadIdx.x;
  const float4* xr = (const float4*)(X + (size_t)row * D);
  float4 v[PER];
  float m = 0.f;
  #pragma unroll
  for (int i = 0; i < PER; ++i) {
    v[i] = xr[tid + 256 * i];
    m = fmaxf(m, fmaxf(fmaxf(fabsf(v[i].x), fabsf(v[i].y)),
                       fmaxf(fabsf(v[i].z), fabsf(v[i].w))));
  }
  #pragma unroll
  for (int off = 32; off >= 1; off >>= 1) m = fmaxf(m, __shfl_xor(m, off));
  __shared__ float wm[4];
  if ((tid & 63) == 0) wm[tid >> 6] = m;
  __syncthreads();
  m = fmaxf(fmaxf(wm[0], wm[1]), fmaxf(wm[2], wm[3]));
  const float s = 127.f / fmaxf(m, 1e-5f);   // same fp32 expr as reference
  if (tid == 0) inv_sa[row] = 1.f / s;
  ushort4* oq = (ushort4*)(Xq + (size_t)row * D);
  #pragma unroll
  for (int i = 0; i < PER; ++i) {
    ushort4 u;
    u.x = f2bf_exact(fminf(fmaxf(rintf(v[i].x * s), -128.f), 127.f));
    u.y = f2bf_exact(fminf(fmaxf(rintf(v[i].y * s), -128.f), 127.f));
    u.z = f2bf_exact(fminf(fmaxf(rintf(v[i].z * s), -128.f), 127.f));
    u.w = f2bf_exact(fminf(fmaxf(rintf(v[i].w * s), -128.f), 127.f));
    oq[tid + 256 * i] = u;
  }
}

// ---------------- GEMM: C[b,o] = sum_i A[b,i]*W[o,i], fused epilogue --------
// m97 structure: 128x128 tile, BK=32, 4 waves (2x2), 4x4 16x16x32 frags/wave,
// global_load_lds width-16 staging, single-buffered LDS.
template<int K, int N, bool TANH>
__global__ __launch_bounds__(256) void gemm_bt(
    const unsigned short* __restrict__ A,   // [M x K] bf16 (integer values)
    const unsigned short* __restrict__ W,   // [N x K] bf16 ternary
    const float* __restrict__ inv_sa,       // [M] 1/act_scale
    const float* __restrict__ wsc, int widx,
    const float* __restrict__ bias,         // [N]
    float* __restrict__ out)                // [M x N] fp32
{
  __shared__ unsigned short As[128 * 32];
  __shared__ unsigned short Bs[128 * 32];
  const int tid = threadIdx.x;
  const int wv = tid >> 6;
  const int ln = tid & 63;
  const int bm = blockIdx.y, bn = blockIdx.x;
  const int wr = wv >> 1, wc = wv & 1;

  const unsigned short* Ab = A + (size_t)bm * 128 * K;
  const unsigned short* Wb = W + (size_t)bn * 128 * K;

  f32x4_t acc[4][4];
  #pragma unroll
  for (int m = 0; m < 4; ++m)
    #pragma unroll
    for (int n = 0; n < 4; ++n)
      acc[m][n] = (f32x4_t){0.f, 0.f, 0.f, 0.f};

  for (int k0 = 0; k0 < K; k0 += 32) {
    // stage 128x32 of A and W: chunk c -> row=c>>2, kcol=(c&3)*8, LDS linear
    #pragma unroll
    for (int l = 0; l < 2; ++l) {
      const int c = l * 256 + wv * 64 + ln;
      const int row = c >> 2;
      const int kc = (c & 3) * 8;
      GLDS16(Ab + (size_t)row * K + k0 + kc, As + (size_t)(l * 256 + wv * 64) * 8);
      GLDS16(Wb + (size_t)row * K + k0 + kc, Bs + (size_t)(l * 256 + wv * 64) * 8);
    }
    __syncthreads();
    bf16x8_t aw[4], bw[4];
    #pragma unroll
    for (int m = 0; m < 4; ++m)
      aw[m] = *(const bf16x8_t*)(As + (wr * 64 + m * 16 + (ln & 15)) * 32 + (ln >> 4) * 8);
    #pragma unroll
    for (int n = 0; n < 4; ++n)
      bw[n] = *(const bf16x8_t*)(Bs + (wc * 64 + n * 16 + (ln & 15)) * 32 + (ln >> 4) * 8);
    #pragma unroll
    for (int m = 0; m < 4; ++m)
      #pragma unroll
      for (int n = 0; n < 4; ++n)
        acc[m][n] = __builtin_amdgcn_mfma_f32_16x16x32_bf16(aw[m], bw[n], acc[m][n], 0, 0, 0);
    __syncthreads();
  }

  const float invw = wsc[widx * 2 + 1];
  #pragma unroll
  for (int m = 0; m < 4; ++m) {
    const int gb0 = bm * 128 + wr * 64 + m * 16 + ((ln >> 4) << 2);
    #pragma unroll
    for (int r = 0; r < 4; ++r) {
      const int gb = gb0 + r;
      const float fa = inv_sa[gb] * invw;
      #pragma unroll
      for (int n = 0; n < 4; ++n) {
        const int go = bn * 128 + wc * 64 + n * 16 + (ln & 15);
        const float v = acc[m][n][r] * fa + bias[go];
        out[(size_t)gb * N + go] = TANH ? tanhf(v) : v;
      }
    }
  }
}

// ---------------- driver ----------------------------------------------------
extern "C" void kernel_launch(void* const* d_in, const int* in_sizes, int n_in,
                              void* d_out, int out_size, void* d_ws, size_t ws_size,
                              hipStream_t stream)
{
  const float* x  = (const float*)d_in[0];
  const float* w1 = (const float*)d_in[1]; const float* b1 = (const float*)d_in[2];
  const float* w2 = (const float*)d_in[3]; const float* b2 = (const float*)d_in[4];
  const float* w3 = (const float*)d_in[5]; const float* b3 = (const float*)d_in[6];
  const float* w4 = (const float*)d_in[7]; const float* b4 = (const float*)d_in[8];
  float* out = (float*)d_out;

  constexpr int B = 8192, DIN = 1024, H = 4096, DOUT = 1024;
  char* ws = (char*)d_ws;
  size_t off = 0;
  float*          hbuf = (float*)(ws + off);          off += (size_t)B * H * 4;   // 128 MB
  unsigned short* xq   = (unsigned short*)(ws + off); off += (size_t)B * H * 2;   // 64 MB
  unsigned short* wq   = (unsigned short*)(ws + off); off += (size_t)H * H * 2;   // 32 MB
  float*          inv_sa = (float*)(ws + off);        off += (size_t)B * 4;
  double*         part = (double*)(ws + off);         off += 1024 * 8;
  float*          wsc  = (float*)(ws + off);          off += 64;

  // per-tensor weight scales (deterministic fp64 reduction -> fp32 like ref)
  absmean_part_k<<<1024, 256, 0, stream>>>(w1, H * DIN / 4, part);
  absmean_fin_k<<<1, 256, 0, stream>>>(part, 1024, (double)H * DIN, wsc, 0);
  absmean_part_k<<<1024, 256, 0, stream>>>(w2, H * H / 4, part);
  absmean_fin_k<<<1, 256, 0, stream>>>(part, 1024, (double)H * H, wsc, 1);
  absmean_part_k<<<1024, 256, 0, stream>>>(w3, H * H / 4, part);
  absmean_fin_k<<<1, 256, 0, stream>>>(part, 1024, (double)H * H, wsc, 2);
  absmean_part_k<<<1024, 256, 0, stream>>>(w4, DOUT * H / 4, part);
  absmean_fin_k<<<1, 256, 0, stream>>>(part, 1024, (double)DOUT * H, wsc, 3);

  // layer 1: x(8192x1024) @ w1^T -> tanh -> hbuf
  act_quant_k<DIN><<<B, 256, 0, stream>>>(x, xq, inv_sa);
  quant_w_k<<<2048, 256, 0, stream>>>(w1, wq, wsc, 0, H * DIN / 4);
  gemm_bt<DIN, H, true><<<dim3(H / 128, B / 128), 256, 0, stream>>>(
      xq, wq, inv_sa, wsc, 0, b1, hbuf);

  // layer 2
  act_quant_k<H><<<B, 256, 0, stream>>>(hbuf, xq, inv_sa);
  quant_w_k<<<2048, 256, 0, stream>>>(w2, wq, wsc, 1, H * H / 4);
  gemm_bt<H, H, true><<<dim3(H / 128, B / 128), 256, 0, stream>>>(
      xq, wq, inv_sa, wsc, 1, b2, hbuf);

  // layer 3
  act_quant_k<H><<<B, 256, 0, stream>>>(hbuf, xq, inv_sa);
  quant_w_k<<<2048, 256, 0, stream>>>(w3, wq, wsc, 2, H * H / 4);
  gemm_bt<H, H, true><<<dim3(H / 128, B / 128), 256, 0, stream>>>(
      xq, wq, inv_sa, wsc, 2, b3, hbuf);

  // layer 4: no tanh, write d_out
  act_quant_k<H><<<B, 256, 0, stream>>>(hbuf, xq, inv_sa);
  quant_w_k<<<2048, 256, 0, stream>>>(w4, wq, wsc, 3, DOUT * H / 4);
  gemm_bt<H, DOUT, false><<<dim3(DOUT / 128, B / 128), 256, 0, stream>>>(
      xq, wq, inv_sa, wsc, 3, b4, out);
}

// Round 2
// 640.120 us; speedup vs baseline: 1.6459x; 1.6459x over previous
//
#include <hip/hip_runtime.h>
#include <hip/hip_bf16.h>

// BitNet 4-layer MLP forward, MI355X — round 2: i8 MFMA.
// Quantized matmuls are integer-exact: q_x in [-128,127], q_w in {-1,0,1}.
// mfma_i32_16x16x64_i8 accumulates exactly in i32 (|sum| <= 4096*128 < 2^24,
// so the i32->f32 epilogue convert is exact). Numerics identical to round 1.

typedef __attribute__((ext_vector_type(4))) int i32x4_t;

#define GLDS16(g, l) __builtin_amdgcn_global_load_lds( \
    (const __attribute__((address_space(1))) unsigned int*)(g), \
    (__attribute__((address_space(3))) unsigned int*)(l), 16, 0, 0)

static __device__ __forceinline__ unsigned char f2i8(float f) {
  return (unsigned char)(int)f;   // f is already rint'ed and clipped
}

// ---------------- weight abs-mean (deterministic two-stage fp64) ------------
__global__ __launch_bounds__(256) void absmean_part_k(
    const float* __restrict__ W, int n4, double* __restrict__ part)
{
  double s = 0.0;
  const int stride = gridDim.x * 256;
  for (int i = blockIdx.x * 256 + threadIdx.x; i < n4; i += stride) {
    float4 v = ((const float4*)W)[i];
    s += (double)fabsf(v.x); s += (double)fabsf(v.y);
    s += (double)fabsf(v.z); s += (double)fabsf(v.w);
  }
  __shared__ double sd[256];
  sd[threadIdx.x] = s;
  __syncthreads();
  for (int st = 128; st > 0; st >>= 1) {
    if (threadIdx.x < st) sd[threadIdx.x] += sd[threadIdx.x + st];
    __syncthreads();
  }
  if (threadIdx.x == 0) part[blockIdx.x] = sd[0];
}

__global__ __launch_bounds__(256) void absmean_fin_k(
    const double* __restrict__ part, int nPart, double n,
    float* __restrict__ wsc, int widx)
{
  __shared__ double sd[256];
  double s = 0.0;
  for (int i = threadIdx.x; i < nPart; i += 256) s += part[i];
  sd[threadIdx.x] = s;
  __syncthreads();
  for (int st = 128; st > 0; st >>= 1) {
    if (threadIdx.x < st) sd[threadIdx.x] += sd[threadIdx.x + st];
    __syncthreads();
  }
  if (threadIdx.x == 0) {
    float mean = (float)(sd[0] / n);
    float scale = 1.f / fmaxf(mean, 1e-5f);   // matches reference fp32 math
    wsc[widx * 2]     = scale;                // used for quantization
    wsc[widx * 2 + 1] = 1.f / scale;          // epilogue (== wq magnitude)
  }
}

// ---------------- weight ternary quantization to i8 {-1,0,1} ----------------
__global__ __launch_bounds__(256) void quant_w_k(
    const float* __restrict__ W, unsigned int* __restrict__ Wq,
    const float* __restrict__ wsc, int widx, int n4)
{
  const float s = wsc[widx * 2];
  const int stride = gridDim.x * 256;
  for (int i = blockIdx.x * 256 + threadIdx.x; i < n4; i += stride) {
    float4 v = ((const float4*)W)[i];
    unsigned int u =
        (unsigned int)f2i8(fminf(fmaxf(rintf(v.x * s), -1.f), 1.f)) |
        ((unsigned int)f2i8(fminf(fmaxf(rintf(v.y * s), -1.f), 1.f)) << 8) |
        ((unsigned int)f2i8(fminf(fmaxf(rintf(v.z * s), -1.f), 1.f)) << 16) |
        ((unsigned int)f2i8(fminf(fmaxf(rintf(v.w * s), -1.f), 1.f)) << 24);
    Wq[i] = u;
  }
}

// ---------------- per-row activation quantization to i8 ---------------------
template<int D>
__global__ __launch_bounds__(256) void act_quant_k(
    const float* __restrict__ X, unsigned int* __restrict__ Xq,
    float* __restrict__ inv_sa)
{
  constexpr int PER = D / 1024;     // float4 chunks per thread (256 threads)
  const int row = blockIdx.x, tid = threadIdx.x;
  const float4* xr = (const float4*)(X + (size_t)row * D);
  float4 v[PER];
  float m = 0.f;
  #pragma unroll
  for (int i = 0; i < PER; ++i) {
    v[i] = xr[tid + 256 * i];
    m = fmaxf(m, fmaxf(fmaxf(fabsf(v[i].x), fabsf(v[i].y)),
                       fmaxf(fabsf(v[i].z), fabsf(v[i].w))));
  }
  #pragma unroll
  for (int off = 32; off >= 1; off >>= 1) m = fmaxf(m, __shfl_xor(m, off));
  __shared__ float wm[4];
  if ((tid & 63) == 0) wm[tid >> 6] = m;
  __syncthreads();
  m = fmaxf(fmaxf(wm[0], wm[1]), fmaxf(wm[2], wm[3]));
  const float s = 127.f / fmaxf(m, 1e-5f);   // same fp32 expr as reference
  if (tid == 0) inv_sa[row] = 1.f / s;
  unsigned int* oq = Xq + (size_t)row * (D / 4);
  #pragma unroll
  for (int i = 0; i < PER; ++i) {
    unsigned int u =
        (unsigned int)f2i8(fminf(fmaxf(rintf(v[i].x * s), -128.f), 127.f)) |
        ((unsigned int)f2i8(fminf(fmaxf(rintf(v[i].y * s), -128.f), 127.f)) << 8) |
        ((unsigned int)f2i8(fminf(fmaxf(rintf(v[i].z * s), -128.f), 127.f)) << 16) |
        ((unsigned int)f2i8(fminf(fmaxf(rintf(v[i].w * s), -128.f), 127.f)) << 24);
    oq[tid + 256 * i] = u;
  }
}

// ---------------- GEMM: C[b,o] = sum_i A[b,i]*W[o,i], fused epilogue --------
// 128x128 tile, BK=64, 4 waves (2x2), 4x4 mfma_i32_16x16x64_i8 frags/wave,
// global_load_lds width-16 staging, single-buffered LDS (2-phase structure).
template<int K, int N, bool TANH>
__global__ __launch_bounds__(256) void gemm_bt(
    const signed char* __restrict__ A,      // [M x K] i8 activations
    const signed char* __restrict__ W,      // [N x K] i8 ternary weights
    const float* __restrict__ inv_sa,       // [M] 1/act_scale
    const float* __restrict__ wsc, int widx,
    const float* __restrict__ bias,         // [N]
    float* __restrict__ out)                // [M x N] fp32
{
  __shared__ __align__(16) signed char As[128 * 64];
  __shared__ __align__(16) signed char Bs[128 * 64];
  const int tid = threadIdx.x;
  const int wv = tid >> 6;
  const int ln = tid & 63;
  const int bm = blockIdx.y, bn = blockIdx.x;
  const int wr = wv >> 1, wc = wv & 1;

  const signed char* Ab = A + (size_t)bm * 128 * K;
  const signed char* Wb = W + (size_t)bn * 128 * K;

  i32x4_t acc[4][4];
  #pragma unroll
  for (int m = 0; m < 4; ++m)
    #pragma unroll
    for (int n = 0; n < 4; ++n)
      acc[m][n] = (i32x4_t){0, 0, 0, 0};

  for (int k0 = 0; k0 < K; k0 += 64) {
    // stage 128x64 i8 of A and W; chunk c -> row=c>>2, kcol=(c&3)*16, LDS linear
    #pragma unroll
    for (int l = 0; l < 2; ++l) {
      const int c = l * 256 + wv * 64 + ln;
      const int row = c >> 2;
      const int kc = (c & 3) * 16;
      GLDS16(Ab + (size_t)row * K + k0 + kc, As + (l * 256 + wv * 64) * 16);
      GLDS16(Wb + (size_t)row * K + k0 + kc, Bs + (l * 256 + wv * 64) * 16);
    }
    __syncthreads();
    i32x4_t aw[4], bw[4];
    #pragma unroll
    for (int m = 0; m < 4; ++m)
      aw[m] = *(const i32x4_t*)(As + (wr * 64 + m * 16 + (ln & 15)) * 64 + (ln >> 4) * 16);
    #pragma unroll
    for (int n = 0; n < 4; ++n)
      bw[n] = *(const i32x4_t*)(Bs + (wc * 64 + n * 16 + (ln & 15)) * 64 + (ln >> 4) * 16);
    #pragma unroll
    for (int m = 0; m < 4; ++m)
      #pragma unroll
      for (int n = 0; n < 4; ++n)
        acc[m][n] = __builtin_amdgcn_mfma_i32_16x16x64_i8(aw[m], bw[n], acc[m][n], 0, 0, 0);
    __syncthreads();
  }

  const float invw = wsc[widx * 2 + 1];
  #pragma unroll
  for (int m = 0; m < 4; ++m) {
    const int gb0 = bm * 128 + wr * 64 + m * 16 + ((ln >> 4) << 2);
    #pragma unroll
    for (int r = 0; r < 4; ++r) {
      const int gb = gb0 + r;
      const float fa = inv_sa[gb] * invw;
      #pragma unroll
      for (int n = 0; n < 4; ++n) {
        const int go = bn * 128 + wc * 64 + n * 16 + (ln & 15);
        const float v = (float)acc[m][n][r] * fa + bias[go];
        out[(size_t)gb * N + go] = TANH ? tanhf(v) : v;
      }
    }
  }
}

// ---------------- driver ----------------------------------------------------
extern "C" void kernel_launch(void* const* d_in, const int* in_sizes, int n_in,
                              void* d_out, int out_size, void* d_ws, size_t ws_size,
                              hipStream_t stream)
{
  const float* x  = (const float*)d_in[0];
  const float* w1 = (const float*)d_in[1]; const float* b1 = (const float*)d_in[2];
  const float* w2 = (const float*)d_in[3]; const float* b2 = (const float*)d_in[4];
  const float* w3 = (const float*)d_in[5]; const float* b3 = (const float*)d_in[6];
  const float* w4 = (const float*)d_in[7]; const float* b4 = (const float*)d_in[8];
  float* out = (float*)d_out;

  constexpr int B = 8192, DIN = 1024, H = 4096, DOUT = 1024;
  char* ws = (char*)d_ws;
  size_t off = 0;
  float*       hbuf = (float*)(ws + off);        off += (size_t)B * H * 4;   // 128 MB
  signed char* xq   = (signed char*)(ws + off);  off += (size_t)B * H;       // 32 MB
  signed char* wq   = (signed char*)(ws + off);  off += (size_t)H * H;       // 16 MB
  float*       inv_sa = (float*)(ws + off);      off += (size_t)B * 4;
  double*      part = (double*)(ws + off);       off += 1024 * 8;
  float*       wsc  = (float*)(ws + off);        off += 64;

  // per-tensor weight scales (deterministic fp64 reduction -> fp32 like ref)
  absmean_part_k<<<1024, 256, 0, stream>>>(w1, H * DIN / 4, part);
  absmean_fin_k<<<1, 256, 0, stream>>>(part, 1024, (double)H * DIN, wsc, 0);
  absmean_part_k<<<1024, 256, 0, stream>>>(w2, H * H / 4, part);
  absmean_fin_k<<<1, 256, 0, stream>>>(part, 1024, (double)H * H, wsc, 1);
  absmean_part_k<<<1024, 256, 0, stream>>>(w3, H * H / 4, part);
  absmean_fin_k<<<1, 256, 0, stream>>>(part, 1024, (double)H * H, wsc, 2);
  absmean_part_k<<<1024, 256, 0, stream>>>(w4, DOUT * H / 4, part);
  absmean_fin_k<<<1, 256, 0, stream>>>(part, 1024, (double)DOUT * H, wsc, 3);

  // layer 1: x(8192x1024) @ w1^T -> tanh -> hbuf
  act_quant_k<DIN><<<B, 256, 0, stream>>>(x, (unsigned int*)xq, inv_sa);
  quant_w_k<<<2048, 256, 0, stream>>>(w1, (unsigned int*)wq, wsc, 0, H * DIN / 4);
  gemm_bt<DIN, H, true><<<dim3(H / 128, B / 128), 256, 0, stream>>>(
      xq, wq, inv_sa, wsc, 0, b1, hbuf);

  // layer 2
  act_quant_k<H><<<B, 256, 0, stream>>>(hbuf, (unsigned int*)xq, inv_sa);
  quant_w_k<<<2048, 256, 0, stream>>>(w2, (unsigned int*)wq, wsc, 1, H * H / 4);
  gemm_bt<H, H, true><<<dim3(H / 128, B / 128), 256, 0, stream>>>(
      xq, wq, inv_sa, wsc, 1, b2, hbuf);

  // layer 3
  act_quant_k<H><<<B, 256, 0, stream>>>(hbuf, (unsigned int*)xq, inv_sa);
  quant_w_k<<<2048, 256, 0, stream>>>(w3, (unsigned int*)wq, wsc, 2, H * H / 4);
  gemm_bt<H, H, true><<<dim3(H / 128, B / 128), 256, 0, stream>>>(
      xq, wq, inv_sa, wsc, 2, b3, hbuf);

  // layer 4: no tanh, write d_out
  act_quant_k<H><<<B, 256, 0, stream>>>(hbuf, (unsigned int*)xq, inv_sa);
  quant_w_k<<<2048, 256, 0, stream>>>(w4, (unsigned int*)wq, wsc, 3, DOUT * H / 4);
  gemm_bt<H, DOUT, false><<<dim3(DOUT / 128, B / 128), 256, 0, stream>>>(
      xq, wq, inv_sa, wsc, 3, b4, out);
}